// Round 8
// baseline (222.188 us; speedup 1.0000x reference)
//
#include <hip/hip_runtime.h>
#include <hip/hip_bf16.h>
#include <stdint.h>

typedef __attribute__((ext_vector_type(8))) short bf16x8;
typedef __attribute__((ext_vector_type(4))) float f32x4;

__device__ __forceinline__ unsigned short f2bf(float f) {
  __hip_bfloat16 h = __float2bfloat16(f);
  return *reinterpret_cast<unsigned short*>(&h);
}

// ---------------- fused: absmax(w1/w2) (y=0/1) + x->bf16 cast (y=2) ----------------
__global__ void prep_kernel(const float* __restrict__ w1, const float* __restrict__ w2,
                            const float* __restrict__ x, int n4w, int n4x,
                            unsigned int* __restrict__ out_scales,
                            unsigned short* __restrict__ ox) {
  if (blockIdx.y == 2) {
    const float4* x4 = reinterpret_cast<const float4*>(x);
    ushort4* o4 = reinterpret_cast<ushort4*>(ox);
    for (int i = blockIdx.x * blockDim.x + threadIdx.x; i < n4x;
         i += gridDim.x * blockDim.x) {
      float4 v = x4[i];
      o4[i] = make_ushort4(f2bf(v.x), f2bf(v.y), f2bf(v.z), f2bf(v.w));
    }
    return;
  }
  const float* w = blockIdx.y ? w2 : w1;
  __shared__ unsigned int red[256];
  unsigned int m = 0u;
  const uint4* w4 = reinterpret_cast<const uint4*>(w);
  for (int i = blockIdx.x * blockDim.x + threadIdx.x; i < n4w;
       i += gridDim.x * blockDim.x) {
    uint4 v = w4[i];
    m = max(m, v.x & 0x7fffffffu);
    m = max(m, v.y & 0x7fffffffu);
    m = max(m, v.z & 0x7fffffffu);
    m = max(m, v.w & 0x7fffffffu);
  }
  red[threadIdx.x] = m;
  __syncthreads();
  for (int s = 128; s > 0; s >>= 1) {
    if ((int)threadIdx.x < s)
      red[threadIdx.x] = max(red[threadIdx.x], red[threadIdx.x + s]);
    __syncthreads();
  }
  if (threadIdx.x == 0) atomicMax(out_scales + blockIdx.y, red[0]);
}

// ---------------- fake-quant w1/w2 (round-half-even) + cast to bf16 ----------------
__global__ void quant2_kernel(const float* __restrict__ w1, const float* __restrict__ w2,
                              int n4, const unsigned int* __restrict__ maxbits,
                              const int* __restrict__ bits,
                              unsigned short* __restrict__ o1, unsigned short* __restrict__ o2) {
  const float* w = blockIdx.y ? w2 : w1;
  unsigned short* o = blockIdx.y ? o2 : o1;
  const float qmax = (float)((1 << (*bits - 1)) - 1);
  const float scale = __uint_as_float(maxbits[blockIdx.y]) / qmax;
  const float4* w4 = reinterpret_cast<const float4*>(w);
  ushort4* o4 = reinterpret_cast<ushort4*>(o);
  for (int i = blockIdx.x * blockDim.x + threadIdx.x; i < n4;
       i += gridDim.x * blockDim.x) {
    float4 v = w4[i];
    float a = fminf(fmaxf(rintf(v.x / scale), -qmax), qmax) * scale;
    float b = fminf(fmaxf(rintf(v.y / scale), -qmax), qmax) * scale;
    float c = fminf(fmaxf(rintf(v.z / scale), -qmax), qmax) * scale;
    float d = fminf(fmaxf(rintf(v.w / scale), -qmax), qmax) * scale;
    o4[i] = make_ushort4(f2bf(a), f2bf(b), f2bf(c), f2bf(d));
  }
}

// ======== common: 8-wave 256x256 tile, 2M x 4N waves, wave tile 128x64 ========
// Swizzle (T2, rule 21): LDS linear; global source slot ^= derived row bits;
// same XOR on ds_read. Rounds 3-7 measured: 0 bank conflicts.
// Epilogue: C/D layout col=lane&15, row=(lane>>4)*4+rr  [m89/m91 verified].

// ---------------- GEMM1 kernel: BK=32, 2 phases/K-tile, 64KB LDS (2 blk/CU) ----------------
// Ledger (1-tile-ahead): P0 issues SA(t+1) then vmcnt(2) (only SA(t+1)'s 2
// loads may remain); P1 issues SB(t+1), no wait. Buffer X[b^1] is restaged
// only after the end-barrier of the last phase that read it (checked per
// region). Last tile: vmcnt(0), no staging.
template<bool RELU, bool BF16_OUT>
__global__ __launch_bounds__(512, 2)
void gemm8w32(const unsigned short* __restrict__ A,  // [M,K] bf16 bits
              const unsigned short* __restrict__ B,  // [N,K] bf16 bits
              const float* __restrict__ bias,        // [N]
              void* __restrict__ Cout,               // [M,N] bf16 or f32
              int M, int N, int K, int gx) {
  __shared__ __attribute__((aligned(16))) unsigned short Abuf[2][256 * 32];
  __shared__ __attribute__((aligned(16))) unsigned short Bbuf[2][256 * 32];

  // bijective XCD swizzle (T1/m204)
  const int nwg = gridDim.x;
  const int orig = blockIdx.x;
  const int q = nwg >> 3, r = nwg & 7;
  const int xcd = orig & 7, cidx = orig >> 3;
  const int wgid = (xcd < r ? xcd * (q + 1) : r * (q + 1) + (xcd - r) * q) + cidx;
  const int bx = wgid % gx;
  const int by = wgid / gx;

  const int tid = threadIdx.x;
  const int lane = tid & 63;
  const int wave = tid >> 6;
  const int wr = wave >> 2;   // 0..1 : 128-row band
  const int wc = wave & 3;    // 0..3 : 64-col band
  const long brow = (long)by * 256;
  const long bcol = (long)bx * 256;

  f32x4 acc[8][4] = {};

  const int fr = lane & 15;
  const int fq = lane >> 4;                               // 16B k-slot 0..3
  const int swz8 = ((lane & 3) ^ ((lane >> 3) & 3)) * 8;  // staging src slot
  const int sgrow = wave * 16 + (lane >> 2);              // staging row in 128-chunk

  auto SA = [&](int tt) {
    unsigned short* dst = &Abuf[tt & 1][wave * 16 * 32];
    const unsigned short* g = A + (brow + sgrow) * (long)K + tt * 32 + swz8;
#pragma unroll
    for (int c = 0; c < 2; ++c)
      __builtin_amdgcn_global_load_lds(
          (const __attribute__((address_space(1))) void*)(g + (long)c * 128 * K),
          (__attribute__((address_space(3))) void*)(dst + c * 128 * 32), 16, 0, 0);
  };
  auto SB = [&](int tt) {
    unsigned short* dst = &Bbuf[tt & 1][wave * 16 * 32];
    const unsigned short* g = B + (bcol + sgrow) * (long)K + tt * 32 + swz8;
#pragma unroll
    for (int c = 0; c < 2; ++c)
      __builtin_amdgcn_global_load_lds(
          (const __attribute__((address_space(1))) void*)(g + (long)c * 128 * K),
          (__attribute__((address_space(3))) void*)(dst + c * 128 * 32), 16, 0, 0);
  };
  auto RDA = [&](int b, int mseg, bf16x8* a) {
    const unsigned short* base = &Abuf[b][0];
#pragma unroll
    for (int mi = 0; mi < 4; ++mi) {
      const int row = wr * 128 + mseg * 64 + mi * 16 + fr;
      a[mi] = *reinterpret_cast<const bf16x8*>(base + row * 32 + ((fq ^ ((row >> 1) & 3)) * 8));
    }
  };
  auto RDB = [&](int b, bf16x8* bb) {
    const unsigned short* base = &Bbuf[b][0];
#pragma unroll
    for (int ni = 0; ni < 4; ++ni) {
      const int row = wc * 64 + ni * 16 + fr;
      bb[ni] = *reinterpret_cast<const bf16x8*>(base + row * 32 + ((fq ^ ((row >> 1) & 3)) * 8));
    }
  };
  auto MM = [&](int mseg, bf16x8* a, bf16x8* bb) {
#pragma unroll
    for (int mi = 0; mi < 4; ++mi)
#pragma unroll
      for (int ni = 0; ni < 4; ++ni)
        acc[mseg * 4 + mi][ni] = __builtin_amdgcn_mfma_f32_16x16x32_bf16(
            a[mi], bb[ni], acc[mseg * 4 + mi][ni], 0, 0, 0);
  };

  const int nt = K / 32;
  SA(0); SB(0);

  bf16x8 a[4], bb[4];
  for (int t = 0; t < nt; ++t) {
    const int b = t & 1;
    // ---- P0: mseg0 (+ B frags) ----
    if (t + 1 < nt) {
      SA(t + 1);
      asm volatile("s_waitcnt vmcnt(2)" ::: "memory");
    } else {
      asm volatile("s_waitcnt vmcnt(0)" ::: "memory");
    }
    asm volatile("s_barrier" ::: "memory");
    RDA(b, 0, a); RDB(b, bb);
    asm volatile("s_waitcnt lgkmcnt(0)" ::: "memory");
    __builtin_amdgcn_sched_barrier(0);
    __builtin_amdgcn_s_setprio(1);
    MM(0, a, bb);
    __builtin_amdgcn_s_setprio(0);
    asm volatile("s_barrier" ::: "memory");
    // ---- P1: mseg1 (reuse bb) ----
    if (t + 1 < nt) SB(t + 1);
    RDA(b, 1, a);
    asm volatile("s_waitcnt lgkmcnt(0)" ::: "memory");
    __builtin_amdgcn_sched_barrier(0);
    __builtin_amdgcn_s_setprio(1);
    MM(1, a, bb);
    __builtin_amdgcn_s_setprio(0);
    asm volatile("s_barrier" ::: "memory");
  }

  // epilogue
#pragma unroll
  for (int ni = 0; ni < 4; ++ni) {
    const long col = bcol + wc * 64 + ni * 16 + fr;
    const float bv = bias[col];
#pragma unroll
    for (int mi = 0; mi < 8; ++mi) {
#pragma unroll
      for (int rr = 0; rr < 4; ++rr) {
        const long row = brow + wr * 128 + mi * 16 + fq * 4 + rr;
        float v = acc[mi][ni][rr] + bv;
        if (RELU) v = fmaxf(v, 0.0f);
        if (BF16_OUT)
          ((unsigned short*)Cout)[row * N + col] = f2bf(v);
        else
          ((float*)Cout)[row * N + col] = v;
      }
    }
  }
}

// ---------------- GEMM2 kernel: BK=64, 4 phases/K-tile, 128KB dyn LDS (round-7 proven) ----------------
template<bool RELU, bool BF16_OUT>
__global__ __launch_bounds__(512, 2)
void gemm8w64(const unsigned short* __restrict__ A, const unsigned short* __restrict__ B,
              const float* __restrict__ bias, void* __restrict__ Cout,
              int M, int N, int K, int gx) {
  extern __shared__ unsigned short lds[];  // A: [0,32768) ; B: [32768,65536)

  const int nwg = gridDim.x;
  const int orig = blockIdx.x;
  const int q = nwg >> 3, r = nwg & 7;
  const int xcd = orig & 7, cidx = orig >> 3;
  const int wgid = (xcd < r ? xcd * (q + 1) : r * (q + 1) + (xcd - r) * q) + cidx;
  const int bx = wgid % gx;
  const int by = wgid / gx;

  const int tid = threadIdx.x;
  const int lane = tid & 63;
  const int wave = tid >> 6;
  const int wr = wave >> 2;
  const int wc = wave & 3;
  const long brow = (long)by * 256;
  const long bcol = (long)bx * 256;

  f32x4 acc[8][4] = {};

  const int fr = lane & 15;
  const int fq = lane >> 4;
  const int swz8 = ((lane & 3) ^ ((lane >> 3) & 3)) * 8;
  const int sgrow = wave * 16 + (lane >> 2);

  auto SA = [&](int t, int kh) {
    unsigned short* dst = lds + ((t & 1) * 2 + kh) * 8192 + wave * 16 * 32;
    const unsigned short* g = A + (brow + sgrow) * (long)K + t * 64 + kh * 32 + swz8;
#pragma unroll
    for (int c = 0; c < 2; ++c)
      __builtin_amdgcn_global_load_lds(
          (const __attribute__((address_space(1))) void*)(g + (long)c * 128 * K),
          (__attribute__((address_space(3))) void*)(dst + c * 128 * 32), 16, 0, 0);
  };
  auto SB = [&](int t, int kh) {
    unsigned short* dst = lds + 32768 + ((t & 1) * 2 + kh) * 8192 + wave * 16 * 32;
    const unsigned short* g = B + (bcol + sgrow) * (long)K + t * 64 + kh * 32 + swz8;
#pragma unroll
    for (int c = 0; c < 2; ++c)
      __builtin_amdgcn_global_load_lds(
          (const __attribute__((address_space(1))) void*)(g + (long)c * 128 * K),
          (__attribute__((address_space(3))) void*)(dst + c * 128 * 32), 16, 0, 0);
  };
  auto RDA = [&](int b, int ks, int mseg, bf16x8* a) {
    const unsigned short* base = lds + (b * 2 + ks) * 8192;
#pragma unroll
    for (int mi = 0; mi < 4; ++mi) {
      const int row = wr * 128 + mseg * 64 + mi * 16 + fr;
      a[mi] = *reinterpret_cast<const bf16x8*>(base + row * 32 + ((fq ^ ((row >> 1) & 3)) * 8));
    }
  };
  auto RDB = [&](int b, int ks, bf16x8* bb) {
    const unsigned short* base = lds + 32768 + (b * 2 + ks) * 8192;
#pragma unroll
    for (int ni = 0; ni < 4; ++ni) {
      const int row = wc * 64 + ni * 16 + fr;
      bb[ni] = *reinterpret_cast<const bf16x8*>(base + row * 32 + ((fq ^ ((row >> 1) & 3)) * 8));
    }
  };
  auto MM = [&](int mseg, bf16x8* a, bf16x8* bb) {
#pragma unroll
    for (int mi = 0; mi < 4; ++mi)
#pragma unroll
      for (int ni = 0; ni < 4; ++ni)
        acc[mseg * 4 + mi][ni] = __builtin_amdgcn_mfma_f32_16x16x32_bf16(
            a[mi], bb[ni], acc[mseg * 4 + mi][ni], 0, 0, 0);
  };

  const int nt = K / 64;
  SA(0, 0); SB(0, 0); SA(0, 1); SB(0, 1); SA(1, 0); SB(1, 0);

  bf16x8 a[4], bb[4];
  for (int t = 0; t < nt; ++t) {
    const int b = t & 1;
    // ---- P0 ----
    if (t + 1 < nt) {
      SA(t + 1, 1);
      asm volatile("s_waitcnt vmcnt(10)" ::: "memory");
    } else {
      asm volatile("s_waitcnt vmcnt(4)" ::: "memory");
    }
    asm volatile("s_barrier" ::: "memory");
    RDA(b, 0, 0, a); RDB(b, 0, bb);
    asm volatile("s_waitcnt lgkmcnt(0)" ::: "memory");
    __builtin_amdgcn_sched_barrier(0);
    __builtin_amdgcn_s_setprio(1);
    MM(0, a, bb);
    __builtin_amdgcn_s_setprio(0);
    asm volatile("s_barrier" ::: "memory");
    // ---- P1 ----
    if (t + 1 < nt) SB(t + 1, 1);
    RDA(b, 0, 1, a);
    asm volatile("s_waitcnt lgkmcnt(0)" ::: "memory");
    __builtin_amdgcn_sched_barrier(0);
    __builtin_amdgcn_s_setprio(1);
    MM(1, a, bb);
    __builtin_amdgcn_s_setprio(0);
    asm volatile("s_barrier" ::: "memory");
    // ---- P2 ----
    if (t + 2 < nt) SA(t + 2, 0);
    if (t + 3 <= nt)      asm volatile("s_waitcnt vmcnt(10)" ::: "memory");
    else if (t == nt - 2) asm volatile("s_waitcnt vmcnt(8)"  ::: "memory");
    else                  asm volatile("s_waitcnt vmcnt(0)"  ::: "memory");
    asm volatile("s_barrier" ::: "memory");
    RDA(b, 1, 0, a); RDB(b, 1, bb);
    asm volatile("s_waitcnt lgkmcnt(0)" ::: "memory");
    __builtin_amdgcn_sched_barrier(0);
    __builtin_amdgcn_s_setprio(1);
    MM(0, a, bb);
    __builtin_amdgcn_s_setprio(0);
    asm volatile("s_barrier" ::: "memory");
    // ---- P3 ----
    if (t + 2 < nt) SB(t + 2, 0);
    RDA(b, 1, 1, a);
    asm volatile("s_waitcnt lgkmcnt(0)" ::: "memory");
    __builtin_amdgcn_sched_barrier(0);
    __builtin_amdgcn_s_setprio(1);
    MM(1, a, bb);
    __builtin_amdgcn_s_setprio(0);
    asm volatile("s_barrier" ::: "memory");
  }

#pragma unroll
  for (int ni = 0; ni < 4; ++ni) {
    const long col = bcol + wc * 64 + ni * 16 + fr;
    const float bv = bias[col];
#pragma unroll
    for (int mi = 0; mi < 8; ++mi) {
#pragma unroll
      for (int rr = 0; rr < 4; ++rr) {
        const long row = brow + wr * 128 + mi * 16 + fq * 4 + rr;
        float v = acc[mi][ni][rr] + bv;
        if (RELU) v = fmaxf(v, 0.0f);
        if (BF16_OUT)
          ((unsigned short*)Cout)[row * N + col] = f2bf(v);
        else
          ((float*)Cout)[row * N + col] = v;
      }
    }
  }
}

extern "C" void kernel_launch(void* const* d_in, const int* in_sizes, int n_in,
                              void* d_out, int out_size, void* d_ws, size_t ws_size,
                              hipStream_t stream) {
  const float* x  = (const float*)d_in[0];
  const float* w1 = (const float*)d_in[1];
  const float* b1 = (const float*)d_in[2];
  const float* w2 = (const float*)d_in[3];
  const float* b2 = (const float*)d_in[4];
  const int* bits = (const int*)d_in[5];

  const int M = 64 * 196;  // 12544 tokens
  const int D = 768, H = 3072;
  const int nx = M * D;
  const int nw1 = H * D;

  char* ws = (char*)d_ws;
  unsigned int* scales = (unsigned int*)ws;
  unsigned short* xb  = (unsigned short*)(ws + 256);
  unsigned short* w1q = (unsigned short*)(ws + 256 + (size_t)nx * 2);
  unsigned short* w2q = (unsigned short*)(ws + 256 + (size_t)nx * 2 + (size_t)nw1 * 2);
  unsigned short* hb  = (unsigned short*)(ws + 256 + (size_t)nx * 2 + (size_t)nw1 * 4);

  // allow 128KB dynamic LDS for the BK=64 kernel (host-side, capture-safe)
  hipFuncSetAttribute((const void*)gemm8w64<false, false>,
                      hipFuncAttributeMaxDynamicSharedMemorySize, 131072);

  hipMemsetAsync(scales, 0, 8, stream);
  // y=0/1: absmax(w1/w2); y=2: x -> bf16 cast (independent, overlapped)
  prep_kernel<<<dim3(512, 3), 256, 0, stream>>>(w1, w2, x, nw1 / 4, nx / 4, scales, xb);
  quant2_kernel<<<dim3(512, 2), 256, 0, stream>>>(w1, w2, nw1 / 4, scales, bits, w1q, w2q);

  // GEMM1: h = relu(x @ w1^T + b1), [12544,3072] bf16 ; 49x12 = 588 blocks, nt=24, 2 blk/CU
  gemm8w32<true, true><<<(M / 256) * (H / 256), 512, 0, stream>>>(
      xb, w1q, b1, hb, M, H, D, H / 256);
  // GEMM2: out = h @ w2^T + b2, [12544,768] f32 ; 49x3 = 147 blocks, nt=48
  gemm8w64<false, false><<<(M / 256) * (D / 256), 512, 131072, stream>>>(
      hb, w2q, b2, d_out, M, D, H, D / 256);
}

// Round 9
// 214.238 us; speedup vs baseline: 1.0371x; 1.0371x over previous
//
#include <hip/hip_runtime.h>
#include <hip/hip_bf16.h>
#include <stdint.h>

typedef __attribute__((ext_vector_type(8))) short bf16x8;
typedef __attribute__((ext_vector_type(4))) float f32x4;

__device__ __forceinline__ unsigned short f2bf(float f) {
  __hip_bfloat16 h = __float2bfloat16(f);
  return *reinterpret_cast<unsigned short*>(&h);
}

// ---------------- fused: absmax(w1/w2) (y=0/1) + x->bf16 cast (y=2) ----------------
__global__ void prep_kernel(const float* __restrict__ w1, const float* __restrict__ w2,
                            const float* __restrict__ x, int n4w, int n4x,
                            unsigned int* __restrict__ out_scales,
                            unsigned short* __restrict__ ox) {
  if (blockIdx.y == 2) {
    const float4* x4 = reinterpret_cast<const float4*>(x);
    ushort4* o4 = reinterpret_cast<ushort4*>(ox);
    for (int i = blockIdx.x * blockDim.x + threadIdx.x; i < n4x;
         i += gridDim.x * blockDim.x) {
      float4 v = x4[i];
      o4[i] = make_ushort4(f2bf(v.x), f2bf(v.y), f2bf(v.z), f2bf(v.w));
    }
    return;
  }
  const float* w = blockIdx.y ? w2 : w1;
  __shared__ unsigned int red[256];
  unsigned int m = 0u;
  const uint4* w4 = reinterpret_cast<const uint4*>(w);
  for (int i = blockIdx.x * blockDim.x + threadIdx.x; i < n4w;
       i += gridDim.x * blockDim.x) {
    uint4 v = w4[i];
    m = max(m, v.x & 0x7fffffffu);
    m = max(m, v.y & 0x7fffffffu);
    m = max(m, v.z & 0x7fffffffu);
    m = max(m, v.w & 0x7fffffffu);
  }
  red[threadIdx.x] = m;
  __syncthreads();
  for (int s = 128; s > 0; s >>= 1) {
    if ((int)threadIdx.x < s)
      red[threadIdx.x] = max(red[threadIdx.x], red[threadIdx.x + s]);
    __syncthreads();
  }
  if (threadIdx.x == 0) atomicMax(out_scales + blockIdx.y, red[0]);
}

// ---------------- fake-quant w1/w2 (round-half-even) + cast to bf16 ----------------
__global__ void quant2_kernel(const float* __restrict__ w1, const float* __restrict__ w2,
                              int n4, const unsigned int* __restrict__ maxbits,
                              const int* __restrict__ bits,
                              unsigned short* __restrict__ o1, unsigned short* __restrict__ o2) {
  const float* w = blockIdx.y ? w2 : w1;
  unsigned short* o = blockIdx.y ? o2 : o1;
  const float qmax = (float)((1 << (*bits - 1)) - 1);
  const float scale = __uint_as_float(maxbits[blockIdx.y]) / qmax;
  const float4* w4 = reinterpret_cast<const float4*>(w);
  ushort4* o4 = reinterpret_cast<ushort4*>(o);
  for (int i = blockIdx.x * blockDim.x + threadIdx.x; i < n4;
       i += gridDim.x * blockDim.x) {
    float4 v = w4[i];
    float a = fminf(fmaxf(rintf(v.x / scale), -qmax), qmax) * scale;
    float b = fminf(fmaxf(rintf(v.y / scale), -qmax), qmax) * scale;
    float c = fminf(fmaxf(rintf(v.z / scale), -qmax), qmax) * scale;
    float d = fminf(fmaxf(rintf(v.w / scale), -qmax), qmax) * scale;
    o4[i] = make_ushort4(f2bf(a), f2bf(b), f2bf(c), f2bf(d));
  }
}

// ---------------- GEMM1: round-4 structure (best measured: 93us) + swapped-MFMA epilogue ----
// 128x128 tile, BK=64, 4 waves (2x2), wave tile 64x64. dbuf, 2-deep prefetch,
// counted vmcnt(8). Swizzle (rule 21): linear LDS, global source slot ^= row&7,
// same XOR on ds_read (0 conflicts, rounds 3-8).
// SWAPPED MFMA: acc[m][n] = mfma(b[n], a[m], acc) -> lane holds C^T fragment:
// C-row = lane&15, C-cols = (lane>>4)*4 + {0..3} (4 CONSECUTIVE cols) ->
// epilogue packs 4 bf16 = 8B per store (16 stores/thread vs 128 scalar).
template<bool RELU, bool BF16_OUT>
__global__ __launch_bounds__(256)
void gemm1_bt(const unsigned short* __restrict__ A,  // [M,K] bf16 bits
              const unsigned short* __restrict__ B,  // [N,K] bf16 bits
              const float* __restrict__ bias,        // [N]
              void* __restrict__ Cout,               // [M,N] bf16 or f32
              int M, int N, int K, int gx) {
  constexpr int BK = 64, MF = 4;
  __shared__ __attribute__((aligned(16))) unsigned short As[2][128 * BK];
  __shared__ __attribute__((aligned(16))) unsigned short Bs[2][128 * BK];

  // bijective XCD swizzle (T1/m204)
  const int nwg = gridDim.x;
  const int orig = blockIdx.x;
  const int q = nwg >> 3, r = nwg & 7;
  const int xcd = orig & 7, cidx = orig >> 3;
  const int wgid = (xcd < r ? xcd * (q + 1) : r * (q + 1) + (xcd - r) * q) + cidx;
  const int bx = wgid % gx;
  const int by = wgid / gx;

  const int tid = threadIdx.x;
  const int lane = tid & 63;
  const int wave = tid >> 6;
  const int wr = wave >> 1;
  const int wc = wave & 1;
  const long brow = (long)by * 128;
  const long bcol = (long)bx * 128;

  f32x4 acc[MF][4] = {};

  // staging: chunk = 8 rows x 64 elems (1KB); global slot pre-swizzled
  const int srow = lane >> 3;
  const int gslot = ((lane & 7) ^ (lane >> 3)) * 8;
  const int fr = lane & 15;
  const int fs = lane >> 4;

  auto stage = [&](int k0, int b) {
#pragma unroll
    for (int it = 0; it < 4; ++it) {
      const int c = it * 4 + wave;
      const unsigned short* ga = A + (brow + c * 8 + srow) * (long)K + k0 + gslot;
      __builtin_amdgcn_global_load_lds(
          (const __attribute__((address_space(1))) void*)ga,
          (__attribute__((address_space(3))) void*)(&As[b][c * 512]), 16, 0, 0);
    }
#pragma unroll
    for (int it = 0; it < 4; ++it) {
      const int c = it * 4 + wave;
      const unsigned short* gb = B + (bcol + c * 8 + srow) * (long)K + k0 + gslot;
      __builtin_amdgcn_global_load_lds(
          (const __attribute__((address_space(1))) void*)gb,
          (__attribute__((address_space(3))) void*)(&Bs[b][c * 512]), 16, 0, 0);
    }
  };

  const int nt = K / BK;
  stage(0, 0);
  stage(BK, 1);

  for (int t = 0; t < nt; ++t) {
    const int b = t & 1;
    if (t < nt - 1) asm volatile("s_waitcnt vmcnt(8)" ::: "memory");
    else            asm volatile("s_waitcnt vmcnt(0)" ::: "memory");
    __builtin_amdgcn_s_barrier();

    const unsigned short* as = &As[b][0];
    const unsigned short* bs = &Bs[b][0];
#pragma unroll
    for (int kk = 0; kk < 2; ++kk) {
      const int s = kk * 4 + fs;
      bf16x8 a[MF], bb[4];
#pragma unroll
      for (int m = 0; m < MF; ++m) {
        const int row = wr * 64 + m * 16 + fr;
        a[m] = *reinterpret_cast<const bf16x8*>(as + row * BK + ((s ^ (row & 7)) * 8));
      }
#pragma unroll
      for (int n = 0; n < 4; ++n) {
        const int row = wc * 64 + n * 16 + fr;
        bb[n] = *reinterpret_cast<const bf16x8*>(bs + row * BK + ((s ^ (row & 7)) * 8));
      }
      // SWAPPED operands: output fragment is C^T layout (row=lane&15, 4 consec cols)
#pragma unroll
      for (int m = 0; m < MF; ++m)
#pragma unroll
        for (int n = 0; n < 4; ++n)
          acc[m][n] = __builtin_amdgcn_mfma_f32_16x16x32_bf16(bb[n], a[m], acc[m][n], 0, 0, 0);
    }

    asm volatile("s_waitcnt lgkmcnt(0)" ::: "memory");
    __builtin_amdgcn_sched_barrier(0);
    __builtin_amdgcn_s_barrier();
    if (t + 2 < nt) stage((t + 2) * BK, b);
  }

  // epilogue (swapped layout): row = ...+fr ; cols = ...+n*16+fq*4+{0..3}
  const int colq = fs * 4;  // fs = lane>>4
  float4 bv[4];
#pragma unroll
  for (int n = 0; n < 4; ++n)
    bv[n] = *reinterpret_cast<const float4*>(&bias[bcol + wc * 64 + n * 16 + colq]);
#pragma unroll
  for (int m = 0; m < MF; ++m) {
    const long row = brow + wr * 64 + m * 16 + fr;
#pragma unroll
    for (int n = 0; n < 4; ++n) {
      const long cb = bcol + wc * 64 + n * 16 + colq;
      float v0 = acc[m][n][0] + bv[n].x;
      float v1 = acc[m][n][1] + bv[n].y;
      float v2 = acc[m][n][2] + bv[n].z;
      float v3 = acc[m][n][3] + bv[n].w;
      if (RELU) {
        v0 = fmaxf(v0, 0.0f); v1 = fmaxf(v1, 0.0f);
        v2 = fmaxf(v2, 0.0f); v3 = fmaxf(v3, 0.0f);
      }
      if (BF16_OUT) {
        uint2 o;
        o.x = (unsigned int)f2bf(v0) | ((unsigned int)f2bf(v1) << 16);
        o.y = (unsigned int)f2bf(v2) | ((unsigned int)f2bf(v3) << 16);
        *reinterpret_cast<uint2*>((unsigned short*)Cout + row * N + cb) = o;
      } else {
        *reinterpret_cast<float4*>((float*)Cout + row * N + cb) = make_float4(v0, v1, v2, v3);
      }
    }
  }
}

// ---------------- GEMM2 kernel: BK=64, 4 phases/K-tile, 128KB dyn LDS (round-7 proven) ----------------
template<bool RELU, bool BF16_OUT>
__global__ __launch_bounds__(512, 2)
void gemm8w64(const unsigned short* __restrict__ A, const unsigned short* __restrict__ B,
              const float* __restrict__ bias, void* __restrict__ Cout,
              int M, int N, int K, int gx) {
  extern __shared__ unsigned short lds[];  // A: [0,32768) ; B: [32768,65536)

  const int nwg = gridDim.x;
  const int orig = blockIdx.x;
  const int q = nwg >> 3, r = nwg & 7;
  const int xcd = orig & 7, cidx = orig >> 3;
  const int wgid = (xcd < r ? xcd * (q + 1) : r * (q + 1) + (xcd - r) * q) + cidx;
  const int bx = wgid % gx;
  const int by = wgid / gx;

  const int tid = threadIdx.x;
  const int lane = tid & 63;
  const int wave = tid >> 6;
  const int wr = wave >> 2;
  const int wc = wave & 3;
  const long brow = (long)by * 256;
  const long bcol = (long)bx * 256;

  f32x4 acc[8][4] = {};

  const int fr = lane & 15;
  const int fq = lane >> 4;
  const int swz8 = ((lane & 3) ^ ((lane >> 3) & 3)) * 8;
  const int sgrow = wave * 16 + (lane >> 2);

  auto SA = [&](int t, int kh) {
    unsigned short* dst = lds + ((t & 1) * 2 + kh) * 8192 + wave * 16 * 32;
    const unsigned short* g = A + (brow + sgrow) * (long)K + t * 64 + kh * 32 + swz8;
#pragma unroll
    for (int c = 0; c < 2; ++c)
      __builtin_amdgcn_global_load_lds(
          (const __attribute__((address_space(1))) void*)(g + (long)c * 128 * K),
          (__attribute__((address_space(3))) void*)(dst + c * 128 * 32), 16, 0, 0);
  };
  auto SB = [&](int t, int kh) {
    unsigned short* dst = lds + 32768 + ((t & 1) * 2 + kh) * 8192 + wave * 16 * 32;
    const unsigned short* g = B + (bcol + sgrow) * (long)K + t * 64 + kh * 32 + swz8;
#pragma unroll
    for (int c = 0; c < 2; ++c)
      __builtin_amdgcn_global_load_lds(
          (const __attribute__((address_space(1))) void*)(g + (long)c * 128 * K),
          (__attribute__((address_space(3))) void*)(dst + c * 128 * 32), 16, 0, 0);
  };
  auto RDA = [&](int b, int ks, int mseg, bf16x8* a) {
    const unsigned short* base = lds + (b * 2 + ks) * 8192;
#pragma unroll
    for (int mi = 0; mi < 4; ++mi) {
      const int row = wr * 128 + mseg * 64 + mi * 16 + fr;
      a[mi] = *reinterpret_cast<const bf16x8*>(base + row * 32 + ((fq ^ ((row >> 1) & 3)) * 8));
    }
  };
  auto RDB = [&](int b, int ks, bf16x8* bb) {
    const unsigned short* base = lds + 32768 + (b * 2 + ks) * 8192;
#pragma unroll
    for (int ni = 0; ni < 4; ++ni) {
      const int row = wc * 64 + ni * 16 + fr;
      bb[ni] = *reinterpret_cast<const bf16x8*>(base + row * 32 + ((fq ^ ((row >> 1) & 3)) * 8));
    }
  };
  auto MM = [&](int mseg, bf16x8* a, bf16x8* bb) {
#pragma unroll
    for (int mi = 0; mi < 4; ++mi)
#pragma unroll
      for (int ni = 0; ni < 4; ++ni)
        acc[mseg * 4 + mi][ni] = __builtin_amdgcn_mfma_f32_16x16x32_bf16(
            a[mi], bb[ni], acc[mseg * 4 + mi][ni], 0, 0, 0);
  };

  const int nt = K / 64;
  SA(0, 0); SB(0, 0); SA(0, 1); SB(0, 1); SA(1, 0); SB(1, 0);

  bf16x8 a[4], bb[4];
  for (int t = 0; t < nt; ++t) {
    const int b = t & 1;
    // ---- P0 ----
    if (t + 1 < nt) {
      SA(t + 1, 1);
      asm volatile("s_waitcnt vmcnt(10)" ::: "memory");
    } else {
      asm volatile("s_waitcnt vmcnt(4)" ::: "memory");
    }
    asm volatile("s_barrier" ::: "memory");
    RDA(b, 0, 0, a); RDB(b, 0, bb);
    asm volatile("s_waitcnt lgkmcnt(0)" ::: "memory");
    __builtin_amdgcn_sched_barrier(0);
    __builtin_amdgcn_s_setprio(1);
    MM(0, a, bb);
    __builtin_amdgcn_s_setprio(0);
    asm volatile("s_barrier" ::: "memory");
    // ---- P1 ----
    if (t + 1 < nt) SB(t + 1, 1);
    RDA(b, 0, 1, a);
    asm volatile("s_waitcnt lgkmcnt(0)" ::: "memory");
    __builtin_amdgcn_sched_barrier(0);
    __builtin_amdgcn_s_setprio(1);
    MM(1, a, bb);
    __builtin_amdgcn_s_setprio(0);
    asm volatile("s_barrier" ::: "memory");
    // ---- P2 ----
    if (t + 2 < nt) SA(t + 2, 0);
    if (t + 3 <= nt)      asm volatile("s_waitcnt vmcnt(10)" ::: "memory");
    else if (t == nt - 2) asm volatile("s_waitcnt vmcnt(8)"  ::: "memory");
    else                  asm volatile("s_waitcnt vmcnt(0)"  ::: "memory");
    asm volatile("s_barrier" ::: "memory");
    RDA(b, 1, 0, a); RDB(b, 1, bb);
    asm volatile("s_waitcnt lgkmcnt(0)" ::: "memory");
    __builtin_amdgcn_sched_barrier(0);
    __builtin_amdgcn_s_setprio(1);
    MM(0, a, bb);
    __builtin_amdgcn_s_setprio(0);
    asm volatile("s_barrier" ::: "memory");
    // ---- P3 ----
    if (t + 2 < nt) SB(t + 2, 0);
    RDA(b, 1, 1, a);
    asm volatile("s_waitcnt lgkmcnt(0)" ::: "memory");
    __builtin_amdgcn_sched_barrier(0);
    __builtin_amdgcn_s_setprio(1);
    MM(1, a, bb);
    __builtin_amdgcn_s_setprio(0);
    asm volatile("s_barrier" ::: "memory");
  }

#pragma unroll
  for (int ni = 0; ni < 4; ++ni) {
    const long col = bcol + wc * 64 + ni * 16 + fr;
    const float bv = bias[col];
#pragma unroll
    for (int mi = 0; mi < 8; ++mi) {
#pragma unroll
      for (int rr = 0; rr < 4; ++rr) {
        const long row = brow + wr * 128 + mi * 16 + fq * 4 + rr;
        float v = acc[mi][ni][rr] + bv;
        if (RELU) v = fmaxf(v, 0.0f);
        if (BF16_OUT)
          ((unsigned short*)Cout)[row * N + col] = f2bf(v);
        else
          ((float*)Cout)[row * N + col] = v;
      }
    }
  }
}

extern "C" void kernel_launch(void* const* d_in, const int* in_sizes, int n_in,
                              void* d_out, int out_size, void* d_ws, size_t ws_size,
                              hipStream_t stream) {
  const float* x  = (const float*)d_in[0];
  const float* w1 = (const float*)d_in[1];
  const float* b1 = (const float*)d_in[2];
  const float* w2 = (const float*)d_in[3];
  const float* b2 = (const float*)d_in[4];
  const int* bits = (const int*)d_in[5];

  const int M = 64 * 196;  // 12544 tokens
  const int D = 768, H = 3072;
  const int nx = M * D;
  const int nw1 = H * D;

  char* ws = (char*)d_ws;
  unsigned int* scales = (unsigned int*)ws;
  unsigned short* xb  = (unsigned short*)(ws + 256);
  unsigned short* w1q = (unsigned short*)(ws + 256 + (size_t)nx * 2);
  unsigned short* w2q = (unsigned short*)(ws + 256 + (size_t)nx * 2 + (size_t)nw1 * 2);
  unsigned short* hb  = (unsigned short*)(ws + 256 + (size_t)nx * 2 + (size_t)nw1 * 4);

  hipFuncSetAttribute((const void*)gemm8w64<false, false>,
                      hipFuncAttributeMaxDynamicSharedMemorySize, 131072);

  hipMemsetAsync(scales, 0, 8, stream);
  prep_kernel<<<dim3(512, 3), 256, 0, stream>>>(w1, w2, x, nw1 / 4, nx / 4, scales, xb);
  quant2_kernel<<<dim3(512, 2), 256, 0, stream>>>(w1, w2, nw1 / 4, scales, bits, w1q, w2q);

  // GEMM1: h = relu(x @ w1^T + b1), [12544,3072] bf16 ; 24x98 = 2352 blocks
  gemm1_bt<true, true><<<(H / 128) * (M / 128), 256, 0, stream>>>(
      xb, w1q, b1, hb, M, H, D, H / 128);
  // GEMM2: out = h @ w2^T + b2, [12544,768] f32 ; 49x3 = 147 blocks, nt=48
  gemm8w64<false, false><<<(M / 256) * (D / 256), 512, 131072, stream>>>(
      hb, w2q, b2, d_out, M, D, H, D / 256);
}

// Round 10
// 211.468 us; speedup vs baseline: 1.0507x; 1.0131x over previous
//
#include <hip/hip_runtime.h>
#include <hip/hip_bf16.h>
#include <stdint.h>

typedef __attribute__((ext_vector_type(8))) short bf16x8;
typedef __attribute__((ext_vector_type(4))) float f32x4;

__device__ __forceinline__ unsigned short f2bf(float f) {
  __hip_bfloat16 h = __float2bfloat16(f);
  return *reinterpret_cast<unsigned short*>(&h);
}

// ---------------- fused: absmax(w1/w2) (y=0/1) + x->bf16 cast (y=2) ----------------
__global__ void prep_kernel(const float* __restrict__ w1, const float* __restrict__ w2,
                            const float* __restrict__ x, int n4w, int n4x,
                            unsigned int* __restrict__ out_scales,
                            unsigned short* __restrict__ ox) {
  if (blockIdx.y == 2) {
    const float4* x4 = reinterpret_cast<const float4*>(x);
    ushort4* o4 = reinterpret_cast<ushort4*>(ox);
    for (int i = blockIdx.x * blockDim.x + threadIdx.x; i < n4x;
         i += gridDim.x * blockDim.x) {
      float4 v = x4[i];
      o4[i] = make_ushort4(f2bf(v.x), f2bf(v.y), f2bf(v.z), f2bf(v.w));
    }
    return;
  }
  const float* w = blockIdx.y ? w2 : w1;
  __shared__ unsigned int red[256];
  unsigned int m = 0u;
  const uint4* w4 = reinterpret_cast<const uint4*>(w);
  for (int i = blockIdx.x * blockDim.x + threadIdx.x; i < n4w;
       i += gridDim.x * blockDim.x) {
    uint4 v = w4[i];
    m = max(m, v.x & 0x7fffffffu);
    m = max(m, v.y & 0x7fffffffu);
    m = max(m, v.z & 0x7fffffffu);
    m = max(m, v.w & 0x7fffffffu);
  }
  red[threadIdx.x] = m;
  __syncthreads();
  for (int s = 128; s > 0; s >>= 1) {
    if ((int)threadIdx.x < s)
      red[threadIdx.x] = max(red[threadIdx.x], red[threadIdx.x + s]);
    __syncthreads();
  }
  if (threadIdx.x == 0) atomicMax(out_scales + blockIdx.y, red[0]);
}

// ---------------- fake-quant w1/w2 (round-half-even) + cast to bf16 ----------------
__global__ void quant2_kernel(const float* __restrict__ w1, const float* __restrict__ w2,
                              int n4, const unsigned int* __restrict__ maxbits,
                              const int* __restrict__ bits,
                              unsigned short* __restrict__ o1, unsigned short* __restrict__ o2) {
  const float* w = blockIdx.y ? w2 : w1;
  unsigned short* o = blockIdx.y ? o2 : o1;
  const float qmax = (float)((1 << (*bits - 1)) - 1);
  const float scale = __uint_as_float(maxbits[blockIdx.y]) / qmax;
  const float4* w4 = reinterpret_cast<const float4*>(w);
  ushort4* o4 = reinterpret_cast<ushort4*>(o);
  for (int i = blockIdx.x * blockDim.x + threadIdx.x; i < n4;
       i += gridDim.x * blockDim.x) {
    float4 v = w4[i];
    float a = fminf(fmaxf(rintf(v.x / scale), -qmax), qmax) * scale;
    float b = fminf(fmaxf(rintf(v.y / scale), -qmax), qmax) * scale;
    float c = fminf(fmaxf(rintf(v.z / scale), -qmax), qmax) * scale;
    float d = fminf(fmaxf(rintf(v.w / scale), -qmax), qmax) * scale;
    o4[i] = make_ushort4(f2bf(a), f2bf(b), f2bf(c), f2bf(d));
  }
}

// ---------------- bf16 GEMM, C[M,N] = A[M,K] * B[N,K]^T + bias, optional ReLU ----------------
// ROUND-4 EXACT structure (best measured: GEMM1 93us): 128x128 tile, BK=64,
// 4 waves (2x2), wave tile 64x64, dbuf LDS (64KB -> 2 blocks/CU), 2-deep
// prefetch, COUNTED vmcnt(8) in steady state (never 0 mid-loop).
// Swizzle (T2 via rule 21): linear LDS; global source slot ^= row&7; same XOR
// on ds_read (rounds 3-9 measured: 0 bank conflicts).
// Used for BOTH GEMMs: GEMM1 (K=768, nt=12) and GEMM2 (K=3072, nt=48, 588
// blocks at 2/CU -> fixes the 256x256 kernel's 0.57 CU fill).
template<bool RELU, bool BF16_OUT>
__global__ __launch_bounds__(256)
void gemm_bt(const unsigned short* __restrict__ A,  // [M,K] bf16 bits
             const unsigned short* __restrict__ B,  // [N,K] bf16 bits
             const float* __restrict__ bias,        // [N]
             void* __restrict__ Cout,               // [M,N] bf16 or f32
             int M, int N, int K, int gx) {
  constexpr int BK = 64, MF = 4;
  __shared__ __attribute__((aligned(16))) unsigned short As[2][128 * BK];
  __shared__ __attribute__((aligned(16))) unsigned short Bs[2][128 * BK];

  // bijective XCD swizzle (T1/m204)
  const int nwg = gridDim.x;
  const int orig = blockIdx.x;
  const int q = nwg >> 3, r = nwg & 7;
  const int xcd = orig & 7, cidx = orig >> 3;
  const int wgid = (xcd < r ? xcd * (q + 1) : r * (q + 1) + (xcd - r) * q) + cidx;
  const int bx = wgid % gx;
  const int by = wgid / gx;

  const int tid = threadIdx.x;
  const int lane = tid & 63;
  const int wave = tid >> 6;
  const int wr = wave >> 1;
  const int wc = wave & 1;
  const long brow = (long)by * 128;
  const long bcol = (long)bx * 128;

  f32x4 acc[MF][4] = {};

  // staging: chunk = 8 rows x 64 elems (1KB); global slot pre-swizzled
  const int srow = lane >> 3;
  const int gslot = ((lane & 7) ^ (lane >> 3)) * 8;
  const int fr = lane & 15;
  const int fs = lane >> 4;

  auto stage = [&](int k0, int b) {
#pragma unroll
    for (int it = 0; it < 4; ++it) {
      const int c = it * 4 + wave;
      const unsigned short* ga = A + (brow + c * 8 + srow) * (long)K + k0 + gslot;
      __builtin_amdgcn_global_load_lds(
          (const __attribute__((address_space(1))) void*)ga,
          (__attribute__((address_space(3))) void*)(&As[b][c * 512]), 16, 0, 0);
    }
#pragma unroll
    for (int it = 0; it < 4; ++it) {
      const int c = it * 4 + wave;
      const unsigned short* gb = B + (bcol + c * 8 + srow) * (long)K + k0 + gslot;
      __builtin_amdgcn_global_load_lds(
          (const __attribute__((address_space(1))) void*)gb,
          (__attribute__((address_space(3))) void*)(&Bs[b][c * 512]), 16, 0, 0);
    }
  };

  const int nt = K / BK;
  stage(0, 0);
  stage(BK, 1);

  for (int t = 0; t < nt; ++t) {
    const int b = t & 1;
    // wait for stage(t); stage(t+1)'s 8 loads stay in flight
    if (t < nt - 1) asm volatile("s_waitcnt vmcnt(8)" ::: "memory");
    else            asm volatile("s_waitcnt vmcnt(0)" ::: "memory");
    __builtin_amdgcn_s_barrier();

    const unsigned short* as = &As[b][0];
    const unsigned short* bs = &Bs[b][0];
#pragma unroll
    for (int kk = 0; kk < 2; ++kk) {
      const int s = kk * 4 + fs;
      bf16x8 a[MF], bb[4];
#pragma unroll
      for (int m = 0; m < MF; ++m) {
        const int row = wr * 64 + m * 16 + fr;
        a[m] = *reinterpret_cast<const bf16x8*>(as + row * BK + ((s ^ (row & 7)) * 8));
      }
#pragma unroll
      for (int n = 0; n < 4; ++n) {
        const int row = wc * 64 + n * 16 + fr;
        bb[n] = *reinterpret_cast<const bf16x8*>(bs + row * BK + ((s ^ (row & 7)) * 8));
      }
#pragma unroll
      for (int m = 0; m < MF; ++m)
#pragma unroll
        for (int n = 0; n < 4; ++n)
          acc[m][n] = __builtin_amdgcn_mfma_f32_16x16x32_bf16(a[m], bb[n], acc[m][n], 0, 0, 0);
    }

    asm volatile("s_waitcnt lgkmcnt(0)" ::: "memory");
    __builtin_amdgcn_sched_barrier(0);
    __builtin_amdgcn_s_barrier();
    if (t + 2 < nt) stage((t + 2) * BK, b);
  }

  // epilogue: C/D layout col=lane&15, row=(lane>>4)*4+rr  [m89/m91 verified]
  const int fq = lane >> 4;
#pragma unroll
  for (int n = 0; n < 4; ++n) {
    const long col = bcol + wc * 64 + n * 16 + fr;
    const float bv = bias[col];
#pragma unroll
    for (int m = 0; m < MF; ++m) {
#pragma unroll
      for (int rr = 0; rr < 4; ++rr) {
        const long row = brow + wr * 64 + m * 16 + fq * 4 + rr;
        float v = acc[m][n][rr] + bv;
        if (RELU) v = fmaxf(v, 0.0f);
        if (BF16_OUT)
          ((unsigned short*)Cout)[row * N + col] = f2bf(v);
        else
          ((float*)Cout)[row * N + col] = v;
      }
    }
  }
}

extern "C" void kernel_launch(void* const* d_in, const int* in_sizes, int n_in,
                              void* d_out, int out_size, void* d_ws, size_t ws_size,
                              hipStream_t stream) {
  const float* x  = (const float*)d_in[0];
  const float* w1 = (const float*)d_in[1];
  const float* b1 = (const float*)d_in[2];
  const float* w2 = (const float*)d_in[3];
  const float* b2 = (const float*)d_in[4];
  const int* bits = (const int*)d_in[5];

  const int M = 64 * 196;  // 12544 tokens
  const int D = 768, H = 3072;
  const int nx = M * D;
  const int nw1 = H * D;

  char* ws = (char*)d_ws;
  unsigned int* scales = (unsigned int*)ws;
  unsigned short* xb  = (unsigned short*)(ws + 256);
  unsigned short* w1q = (unsigned short*)(ws + 256 + (size_t)nx * 2);
  unsigned short* w2q = (unsigned short*)(ws + 256 + (size_t)nx * 2 + (size_t)nw1 * 2);
  unsigned short* hb  = (unsigned short*)(ws + 256 + (size_t)nx * 2 + (size_t)nw1 * 4);

  hipMemsetAsync(scales, 0, 8, stream);
  prep_kernel<<<dim3(512, 3), 256, 0, stream>>>(w1, w2, x, nw1 / 4, nx / 4, scales, xb);
  quant2_kernel<<<dim3(512, 2), 256, 0, stream>>>(w1, w2, nw1 / 4, scales, bits, w1q, w2q);

  // GEMM1: h = relu(x @ w1^T + b1), [12544,3072] bf16 ; 24x98 = 2352 blocks, nt=12
  gemm_bt<true, true><<<(H / 128) * (M / 128), 256, 0, stream>>>(
      xb, w1q, b1, hb, M, H, D, H / 128);
  // GEMM2: out = h @ w2^T + b2, [12544,768] f32 ; 6x98 = 588 blocks, nt=48, 2 blk/CU
  gemm_bt<false, false><<<(D / 128) * (M / 128), 256, 0, stream>>>(
      hb, w2q, b2, d_out, M, D, H, D / 128);
}

// Round 11
// 194.257 us; speedup vs baseline: 1.1438x; 1.0886x over previous
//
#include <hip/hip_runtime.h>
#include <hip/hip_bf16.h>
#include <stdint.h>

typedef __attribute__((ext_vector_type(8))) short bf16x8;
typedef __attribute__((ext_vector_type(4))) float f32x4;

__device__ __forceinline__ unsigned short f2bf(float f) {
  __hip_bfloat16 h = __float2bfloat16(f);
  return *reinterpret_cast<unsigned short*>(&h);
}

// ---------------- fused: absmax(w1/w2) (y=0/1) + x->bf16 cast (y=2) ----------------
__global__ void prep_kernel(const float* __restrict__ w1, const float* __restrict__ w2,
                            const float* __restrict__ x, int n4w, int n4x,
                            unsigned int* __restrict__ out_scales,
                            unsigned short* __restrict__ ox) {
  if (blockIdx.y == 2) {
    const float4* x4 = reinterpret_cast<const float4*>(x);
    ushort4* o4 = reinterpret_cast<ushort4*>(ox);
    for (int i = blockIdx.x * blockDim.x + threadIdx.x; i < n4x;
         i += gridDim.x * blockDim.x) {
      float4 v = x4[i];
      o4[i] = make_ushort4(f2bf(v.x), f2bf(v.y), f2bf(v.z), f2bf(v.w));
    }
    return;
  }
  const float* w = blockIdx.y ? w2 : w1;
  __shared__ unsigned int red[256];
  unsigned int m = 0u;
  const uint4* w4 = reinterpret_cast<const uint4*>(w);
  for (int i = blockIdx.x * blockDim.x + threadIdx.x; i < n4w;
       i += gridDim.x * blockDim.x) {
    uint4 v = w4[i];
    m = max(m, v.x & 0x7fffffffu);
    m = max(m, v.y & 0x7fffffffu);
    m = max(m, v.z & 0x7fffffffu);
    m = max(m, v.w & 0x7fffffffu);
  }
  red[threadIdx.x] = m;
  __syncthreads();
  for (int s = 128; s > 0; s >>= 1) {
    if ((int)threadIdx.x < s)
      red[threadIdx.x] = max(red[threadIdx.x], red[threadIdx.x + s]);
    __syncthreads();
  }
  if (threadIdx.x == 0) atomicMax(out_scales + blockIdx.y, red[0]);
}

// ---------------- fake-quant w1/w2 (round-half-even) + cast to bf16 ----------------
__global__ void quant2_kernel(const float* __restrict__ w1, const float* __restrict__ w2,
                              int n4, const unsigned int* __restrict__ maxbits,
                              const int* __restrict__ bits,
                              unsigned short* __restrict__ o1, unsigned short* __restrict__ o2) {
  const float* w = blockIdx.y ? w2 : w1;
  unsigned short* o = blockIdx.y ? o2 : o1;
  const float qmax = (float)((1 << (*bits - 1)) - 1);
  const float scale = __uint_as_float(maxbits[blockIdx.y]) / qmax;
  const float4* w4 = reinterpret_cast<const float4*>(w);
  ushort4* o4 = reinterpret_cast<ushort4*>(o);
  for (int i = blockIdx.x * blockDim.x + threadIdx.x; i < n4;
       i += gridDim.x * blockDim.x) {
    float4 v = w4[i];
    float a = fminf(fmaxf(rintf(v.x / scale), -qmax), qmax) * scale;
    float b = fminf(fmaxf(rintf(v.y / scale), -qmax), qmax) * scale;
    float c = fminf(fmaxf(rintf(v.z / scale), -qmax), qmax) * scale;
    float d = fminf(fmaxf(rintf(v.w / scale), -qmax), qmax) * scale;
    o4[i] = make_ushort4(f2bf(a), f2bf(b), f2bf(c), f2bf(d));
  }
}

// ---------------- bf16 GEMM, C[M,N] = A[M,K] * B[N,K]^T + bias, optional ReLU ----------------
// ROUND-4 EXACT structure (best measured: GEMM1 93us, GEMM2 ~92us):
// BMx128 tile, BK=64, 4 waves (2x2), dbuf LDS (GEMM1 64KB -> 2 blk/CU,
// GEMM2 48KB -> 3 blk/CU), 2-deep prefetch, COUNTED vmcnt(8/6).
// Swizzle (T2 via rule 21): linear LDS; global source slot ^= row&7; same XOR
// on ds_read (rounds 3-10 measured: 0 bank conflicts).
// PRIO: T5 s_setprio around the MFMA cluster — A/B experiment, GEMM2 only
// (GEMM1 is the control at the round-4 reference).
template<int BM, bool PRIO, bool RELU, bool BF16_OUT>
__global__ __launch_bounds__(256)
void gemm_bt(const unsigned short* __restrict__ A,  // [M,K] bf16 bits
             const unsigned short* __restrict__ B,  // [N,K] bf16 bits
             const float* __restrict__ bias,        // [N]
             void* __restrict__ Cout,               // [M,N] bf16 or f32
             int M, int N, int K, int gx) {
  constexpr int BK = 64;
  constexpr int MF = BM / 32;    // A-frags per wave (BM=128 -> 4, BM=64 -> 2)
  __shared__ __attribute__((aligned(16))) unsigned short As[2][BM * BK];
  __shared__ __attribute__((aligned(16))) unsigned short Bs[2][128 * BK];

  // bijective XCD swizzle (T1/m204)
  const int nwg = gridDim.x;
  const int orig = blockIdx.x;
  const int q = nwg >> 3, r = nwg & 7;
  const int xcd = orig & 7, cidx = orig >> 3;
  const int wgid = (xcd < r ? xcd * (q + 1) : r * (q + 1) + (xcd - r) * q) + cidx;
  const int bx = wgid % gx;
  const int by = wgid / gx;

  const int tid = threadIdx.x;
  const int lane = tid & 63;
  const int wave = tid >> 6;
  const int wr = wave >> 1;
  const int wc = wave & 1;
  const long brow = (long)by * BM;
  const long bcol = (long)bx * 128;

  f32x4 acc[MF][4] = {};

  // staging: chunk = 8 rows x 64 elems (1KB); global slot pre-swizzled
  const int srow = lane >> 3;
  const int gslot = ((lane & 7) ^ (lane >> 3)) * 8;
  const int fr = lane & 15;
  const int fs = lane >> 4;

  auto stage = [&](int k0, int b) {
#pragma unroll
    for (int it = 0; it < BM / 32; ++it) {
      const int c = it * 4 + wave;
      const unsigned short* ga = A + (brow + c * 8 + srow) * (long)K + k0 + gslot;
      __builtin_amdgcn_global_load_lds(
          (const __attribute__((address_space(1))) void*)ga,
          (__attribute__((address_space(3))) void*)(&As[b][c * 512]), 16, 0, 0);
    }
#pragma unroll
    for (int it = 0; it < 4; ++it) {
      const int c = it * 4 + wave;
      const unsigned short* gb = B + (bcol + c * 8 + srow) * (long)K + k0 + gslot;
      __builtin_amdgcn_global_load_lds(
          (const __attribute__((address_space(1))) void*)gb,
          (__attribute__((address_space(3))) void*)(&Bs[b][c * 512]), 16, 0, 0);
    }
  };

  const int nt = K / BK;
  stage(0, 0);
  stage(BK, 1);

  for (int t = 0; t < nt; ++t) {
    const int b = t & 1;
    // wait for stage(t); stage(t+1)'s loads (8 or 6) stay in flight
    if (t < nt - 1) {
      if constexpr (BM == 128) asm volatile("s_waitcnt vmcnt(8)" ::: "memory");
      else                     asm volatile("s_waitcnt vmcnt(6)" ::: "memory");
    } else {
      asm volatile("s_waitcnt vmcnt(0)" ::: "memory");
    }
    __builtin_amdgcn_s_barrier();

    const unsigned short* as = &As[b][0];
    const unsigned short* bs = &Bs[b][0];
#pragma unroll
    for (int kk = 0; kk < 2; ++kk) {
      const int s = kk * 4 + fs;
      bf16x8 a[MF], bb[4];
#pragma unroll
      for (int m = 0; m < MF; ++m) {
        const int row = wr * (MF * 16) + m * 16 + fr;
        a[m] = *reinterpret_cast<const bf16x8*>(as + row * BK + ((s ^ (row & 7)) * 8));
      }
#pragma unroll
      for (int n = 0; n < 4; ++n) {
        const int row = wc * 64 + n * 16 + fr;
        bb[n] = *reinterpret_cast<const bf16x8*>(bs + row * BK + ((s ^ (row & 7)) * 8));
      }
      if (PRIO) __builtin_amdgcn_s_setprio(1);
#pragma unroll
      for (int m = 0; m < MF; ++m)
#pragma unroll
        for (int n = 0; n < 4; ++n)
          acc[m][n] = __builtin_amdgcn_mfma_f32_16x16x32_bf16(a[m], bb[n], acc[m][n], 0, 0, 0);
      if (PRIO) __builtin_amdgcn_s_setprio(0);
    }

    asm volatile("s_waitcnt lgkmcnt(0)" ::: "memory");
    __builtin_amdgcn_sched_barrier(0);
    __builtin_amdgcn_s_barrier();
    if (t + 2 < nt) stage((t + 2) * BK, b);
  }

  // epilogue: C/D layout col=lane&15, row=(lane>>4)*4+rr  [m89/m91 verified]
  const int fq = lane >> 4;
#pragma unroll
  for (int n = 0; n < 4; ++n) {
    const long col = bcol + wc * 64 + n * 16 + fr;
    const float bv = bias[col];
#pragma unroll
    for (int m = 0; m < MF; ++m) {
#pragma unroll
      for (int rr = 0; rr < 4; ++rr) {
        const long row = brow + wr * (MF * 16) + m * 16 + fq * 4 + rr;
        float v = acc[m][n][rr] + bv;
        if (RELU) v = fmaxf(v, 0.0f);
        if (BF16_OUT)
          ((unsigned short*)Cout)[row * N + col] = f2bf(v);
        else
          ((float*)Cout)[row * N + col] = v;
      }
    }
  }
}

extern "C" void kernel_launch(void* const* d_in, const int* in_sizes, int n_in,
                              void* d_out, int out_size, void* d_ws, size_t ws_size,
                              hipStream_t stream) {
  const float* x  = (const float*)d_in[0];
  const float* w1 = (const float*)d_in[1];
  const float* b1 = (const float*)d_in[2];
  const float* w2 = (const float*)d_in[3];
  const float* b2 = (const float*)d_in[4];
  const int* bits = (const int*)d_in[5];

  const int M = 64 * 196;  // 12544 tokens
  const int D = 768, H = 3072;
  const int nx = M * D;
  const int nw1 = H * D;

  char* ws = (char*)d_ws;
  unsigned int* scales = (unsigned int*)ws;
  unsigned short* xb  = (unsigned short*)(ws + 256);
  unsigned short* w1q = (unsigned short*)(ws + 256 + (size_t)nx * 2);
  unsigned short* w2q = (unsigned short*)(ws + 256 + (size_t)nx * 2 + (size_t)nw1 * 2);
  unsigned short* hb  = (unsigned short*)(ws + 256 + (size_t)nx * 2 + (size_t)nw1 * 4);

  hipMemsetAsync(scales, 0, 8, stream);
  prep_kernel<<<dim3(512, 3), 256, 0, stream>>>(w1, w2, x, nw1 / 4, nx / 4, scales, xb);
  quant2_kernel<<<dim3(512, 2), 256, 0, stream>>>(w1, w2, nw1 / 4, scales, bits, w1q, w2q);

  // GEMM1: h = relu(x @ w1^T + b1), [12544,3072] bf16 ; 24x98 = 2352 blocks, nt=12
  // (round-4 reference config, NO setprio -> in-run control)
  gemm_bt<128, false, true, true><<<(H / 128) * (M / 128), 256, 0, stream>>>(
      xb, w1q, b1, hb, M, H, D, H / 128);
  // GEMM2: out = h @ w2^T + b2, [12544,768] f32 ; 6x196 = 1176 blocks, nt=48,
  // 48KB LDS -> 3 blk/CU (round-4 best GEMM2) + T5 setprio A/B
  gemm_bt<64, true, false, false><<<(D / 128) * (M / 64), 256, 0, stream>>>(
      hb, w2q, b2, d_out, M, D, H, D / 128);
}

// Round 12
// 184.419 us; speedup vs baseline: 1.2048x; 1.0533x over previous
//
#include <hip/hip_runtime.h>
#include <hip/hip_bf16.h>
#include <stdint.h>

typedef __attribute__((ext_vector_type(8))) short bf16x8;
typedef __attribute__((ext_vector_type(4))) float f32x4;

__device__ __forceinline__ unsigned short f2bf(float f) {
  __hip_bfloat16 h = __float2bfloat16(f);
  return *reinterpret_cast<unsigned short*>(&h);
}

// ---------------- prep: per-block absmax partials (y=0/1) + x->bf16 cast (y=2) ----------------
// No atomics / no memset: block bx of row y stores its partial max to
// pmax[y*512+bx] (plain store, overwritten every call -> deterministic).
__global__ void prep_kernel(const float* __restrict__ w1, const float* __restrict__ w2,
                            const float* __restrict__ x, int n4w, int n4x,
                            unsigned int* __restrict__ pmax,
                            unsigned short* __restrict__ ox) {
  if (blockIdx.y == 2) {
    const float4* x4 = reinterpret_cast<const float4*>(x);
    ushort4* o4 = reinterpret_cast<ushort4*>(ox);
    for (int i = blockIdx.x * blockDim.x + threadIdx.x; i < n4x;
         i += gridDim.x * blockDim.x) {
      float4 v = x4[i];
      o4[i] = make_ushort4(f2bf(v.x), f2bf(v.y), f2bf(v.z), f2bf(v.w));
    }
    return;
  }
  const float* w = blockIdx.y ? w2 : w1;
  __shared__ unsigned int red[256];
  unsigned int m = 0u;
  const uint4* w4 = reinterpret_cast<const uint4*>(w);
  for (int i = blockIdx.x * blockDim.x + threadIdx.x; i < n4w;
       i += gridDim.x * blockDim.x) {
    uint4 v = w4[i];
    m = max(m, v.x & 0x7fffffffu);
    m = max(m, v.y & 0x7fffffffu);
    m = max(m, v.z & 0x7fffffffu);
    m = max(m, v.w & 0x7fffffffu);
  }
  red[threadIdx.x] = m;
  __syncthreads();
  for (int s = 128; s > 0; s >>= 1) {
    if ((int)threadIdx.x < s)
      red[threadIdx.x] = max(red[threadIdx.x], red[threadIdx.x + s]);
    __syncthreads();
  }
  if (threadIdx.x == 0) pmax[blockIdx.y * 512 + blockIdx.x] = red[0];
}

// ---------------- fake-quant w1/w2: reduce 512 partials, then quantize ----------------
__global__ void quant2_kernel(const float* __restrict__ w1, const float* __restrict__ w2,
                              int n4, const unsigned int* __restrict__ pmax,
                              const int* __restrict__ bits,
                              unsigned short* __restrict__ o1, unsigned short* __restrict__ o2) {
  __shared__ unsigned int red[256];
  const unsigned int* p = pmax + blockIdx.y * 512;
  red[threadIdx.x] = max(p[threadIdx.x], p[threadIdx.x + 256]);
  __syncthreads();
  for (int s = 128; s > 0; s >>= 1) {
    if ((int)threadIdx.x < s)
      red[threadIdx.x] = max(red[threadIdx.x], red[threadIdx.x + s]);
    __syncthreads();
  }
  const float qmax = (float)((1 << (*bits - 1)) - 1);
  const float scale = __uint_as_float(red[0]) / qmax;

  const float* w = blockIdx.y ? w2 : w1;
  unsigned short* o = blockIdx.y ? o2 : o1;
  const float4* w4 = reinterpret_cast<const float4*>(w);
  ushort4* o4 = reinterpret_cast<ushort4*>(o);
  for (int i = blockIdx.x * blockDim.x + threadIdx.x; i < n4;
       i += gridDim.x * blockDim.x) {
    float4 v = w4[i];
    float a = fminf(fmaxf(rintf(v.x / scale), -qmax), qmax) * scale;
    float b = fminf(fmaxf(rintf(v.y / scale), -qmax), qmax) * scale;
    float c = fminf(fmaxf(rintf(v.z / scale), -qmax), qmax) * scale;
    float d = fminf(fmaxf(rintf(v.w / scale), -qmax), qmax) * scale;
    o4[i] = make_ushort4(f2bf(a), f2bf(b), f2bf(c), f2bf(d));
  }
}

// ---------------- GEMM1: 128x128 tile, BK=32, dbuf + counted vmcnt(4), 3 blocks/CU ----------------
// Occupancy experiment: 32KB LDS + launch_bounds(256,3) (VGPR cap 170 > ~152
// needed -> no spill squeeze, unlike round 5's MINW=5 confound).
// Swizzle (rounds 5/6 verified, 0 conflicts): chunk = 16 rows x 32 elems;
// global source slot (lane&3)^((lane>>3)&3); ds_read slot fs^((row>>1)&3).
template<bool RELU, bool BF16_OUT>
__global__ __launch_bounds__(256, 3)
void gemm_bt32(const unsigned short* __restrict__ A,  // [M,K] bf16 bits
               const unsigned short* __restrict__ B,  // [N,K] bf16 bits
               const float* __restrict__ bias,        // [N]
               void* __restrict__ Cout,               // [M,N] bf16 or f32
               int M, int N, int K, int gx) {
  constexpr int BK = 32, MF = 4;
  __shared__ __attribute__((aligned(16))) unsigned short As[2][128 * BK];
  __shared__ __attribute__((aligned(16))) unsigned short Bs[2][128 * BK];

  // bijective XCD swizzle (T1/m204)
  const int nwg = gridDim.x;
  const int orig = blockIdx.x;
  const int q = nwg >> 3, r = nwg & 7;
  const int xcd = orig & 7, cidx = orig >> 3;
  const int wgid = (xcd < r ? xcd * (q + 1) : r * (q + 1) + (xcd - r) * q) + cidx;
  const int bx = wgid % gx;
  const int by = wgid / gx;

  const int tid = threadIdx.x;
  const int lane = tid & 63;
  const int wave = tid >> 6;
  const int wr = wave >> 1;
  const int wc = wave & 1;
  const long brow = (long)by * 128;
  const long bcol = (long)bx * 128;

  f32x4 acc[MF][4] = {};

  // staging: chunk = 16 rows x 32 elems (1KB)
  const int srow = lane >> 2;
  const int gslot = ((lane & 3) ^ ((lane >> 3) & 3)) * 8;
  const int fr = lane & 15;
  const int fs = lane >> 4;   // logical 16B k-slot (0..3)

  auto stage = [&](int k0, int b) {
#pragma unroll
    for (int it = 0; it < 2; ++it) {          // A: 8 chunks of 16 rows
      const int c = it * 4 + wave;
      const unsigned short* ga = A + (brow + c * 16 + srow) * (long)K + k0 + gslot;
      __builtin_amdgcn_global_load_lds(
          (const __attribute__((address_space(1))) void*)ga,
          (__attribute__((address_space(3))) void*)(&As[b][c * 512]), 16, 0, 0);
    }
#pragma unroll
    for (int it = 0; it < 2; ++it) {          // B: 8 chunks
      const int c = it * 4 + wave;
      const unsigned short* gb = B + (bcol + c * 16 + srow) * (long)K + k0 + gslot;
      __builtin_amdgcn_global_load_lds(
          (const __attribute__((address_space(1))) void*)gb,
          (__attribute__((address_space(3))) void*)(&Bs[b][c * 512]), 16, 0, 0);
    }
  };

  const int nt = K / BK;
  stage(0, 0);
  stage(BK, 1);

  for (int t = 0; t < nt; ++t) {
    const int b = t & 1;
    if (t < nt - 1) asm volatile("s_waitcnt vmcnt(4)" ::: "memory");
    else            asm volatile("s_waitcnt vmcnt(0)" ::: "memory");
    __builtin_amdgcn_s_barrier();

    const unsigned short* as = &As[b][0];
    const unsigned short* bs = &Bs[b][0];
    bf16x8 a[MF], bb[4];
#pragma unroll
    for (int m = 0; m < MF; ++m) {
      const int row = wr * 64 + m * 16 + fr;
      a[m] = *reinterpret_cast<const bf16x8*>(as + row * BK + ((fs ^ ((row >> 1) & 3)) * 8));
    }
#pragma unroll
    for (int n = 0; n < 4; ++n) {
      const int row = wc * 64 + n * 16 + fr;
      bb[n] = *reinterpret_cast<const bf16x8*>(bs + row * BK + ((fs ^ ((row >> 1) & 3)) * 8));
    }
#pragma unroll
    for (int m = 0; m < MF; ++m)
#pragma unroll
      for (int n = 0; n < 4; ++n)
        acc[m][n] = __builtin_amdgcn_mfma_f32_16x16x32_bf16(a[m], bb[n], acc[m][n], 0, 0, 0);

    asm volatile("s_waitcnt lgkmcnt(0)" ::: "memory");
    __builtin_amdgcn_sched_barrier(0);
    __builtin_amdgcn_s_barrier();
    if (t + 2 < nt) stage((t + 2) * BK, b);
  }

  // epilogue: C/D layout col=lane&15, row=(lane>>4)*4+rr  [m89/m91 verified]
  const int fq = lane >> 4;
#pragma unroll
  for (int n = 0; n < 4; ++n) {
    const long col = bcol + wc * 64 + n * 16 + fr;
    const float bv = bias[col];
#pragma unroll
    for (int m = 0; m < MF; ++m) {
#pragma unroll
      for (int rr = 0; rr < 4; ++rr) {
        const long row = brow + wr * 64 + m * 16 + fq * 4 + rr;
        float v = acc[m][n][rr] + bv;
        if (RELU) v = fmaxf(v, 0.0f);
        if (BF16_OUT)
          ((unsigned short*)Cout)[row * N + col] = f2bf(v);
        else
          ((float*)Cout)[row * N + col] = v;
      }
    }
  }
}

// ---------------- GEMM2: round-11 kernel frozen (BM=64, BK=64, 3 blk/CU, setprio) ----------------
template<int BM, bool PRIO, bool RELU, bool BF16_OUT>
__global__ __launch_bounds__(256)
void gemm_bt(const unsigned short* __restrict__ A, const unsigned short* __restrict__ B,
             const float* __restrict__ bias, void* __restrict__ Cout,
             int M, int N, int K, int gx) {
  constexpr int BK = 64;
  constexpr int MF = BM / 32;
  __shared__ __attribute__((aligned(16))) unsigned short As[2][BM * BK];
  __shared__ __attribute__((aligned(16))) unsigned short Bs[2][128 * BK];

  const int nwg = gridDim.x;
  const int orig = blockIdx.x;
  const int q = nwg >> 3, r = nwg & 7;
  const int xcd = orig & 7, cidx = orig >> 3;
  const int wgid = (xcd < r ? xcd * (q + 1) : r * (q + 1) + (xcd - r) * q) + cidx;
  const int bx = wgid % gx;
  const int by = wgid / gx;

  const int tid = threadIdx.x;
  const int lane = tid & 63;
  const int wave = tid >> 6;
  const int wr = wave >> 1;
  const int wc = wave & 1;
  const long brow = (long)by * BM;
  const long bcol = (long)bx * 128;

  f32x4 acc[MF][4] = {};

  const int srow = lane >> 3;
  const int gslot = ((lane & 7) ^ (lane >> 3)) * 8;
  const int fr = lane & 15;
  const int fs = lane >> 4;

  auto stage = [&](int k0, int b) {
#pragma unroll
    for (int it = 0; it < BM / 32; ++it) {
      const int c = it * 4 + wave;
      const unsigned short* ga = A + (brow + c * 8 + srow) * (long)K + k0 + gslot;
      __builtin_amdgcn_global_load_lds(
          (const __attribute__((address_space(1))) void*)ga,
          (__attribute__((address_space(3))) void*)(&As[b][c * 512]), 16, 0, 0);
    }
#pragma unroll
    for (int it = 0; it < 4; ++it) {
      const int c = it * 4 + wave;
      const unsigned short* gb = B + (bcol + c * 8 + srow) * (long)K + k0 + gslot;
      __builtin_amdgcn_global_load_lds(
          (const __attribute__((address_space(1))) void*)gb,
          (__attribute__((address_space(3))) void*)(&Bs[b][c * 512]), 16, 0, 0);
    }
  };

  const int nt = K / BK;
  stage(0, 0);
  stage(BK, 1);

  for (int t = 0; t < nt; ++t) {
    const int b = t & 1;
    if (t < nt - 1) {
      if constexpr (BM == 128) asm volatile("s_waitcnt vmcnt(8)" ::: "memory");
      else                     asm volatile("s_waitcnt vmcnt(6)" ::: "memory");
    } else {
      asm volatile("s_waitcnt vmcnt(0)" ::: "memory");
    }
    __builtin_amdgcn_s_barrier();

    const unsigned short* as = &As[b][0];
    const unsigned short* bs = &Bs[b][0];
#pragma unroll
    for (int kk = 0; kk < 2; ++kk) {
      const int s = kk * 4 + fs;
      bf16x8 a[MF], bb[4];
#pragma unroll
      for (int m = 0; m < MF; ++m) {
        const int row = wr * (MF * 16) + m * 16 + fr;
        a[m] = *reinterpret_cast<const bf16x8*>(as + row * BK + ((s ^ (row & 7)) * 8));
      }
#pragma unroll
      for (int n = 0; n < 4; ++n) {
        const int row = wc * 64 + n * 16 + fr;
        bb[n] = *reinterpret_cast<const bf16x8*>(bs + row * BK + ((s ^ (row & 7)) * 8));
      }
      if (PRIO) __builtin_amdgcn_s_setprio(1);
#pragma unroll
      for (int m = 0; m < MF; ++m)
#pragma unroll
        for (int n = 0; n < 4; ++n)
          acc[m][n] = __builtin_amdgcn_mfma_f32_16x16x32_bf16(a[m], bb[n], acc[m][n], 0, 0, 0);
      if (PRIO) __builtin_amdgcn_s_setprio(0);
    }

    asm volatile("s_waitcnt lgkmcnt(0)" ::: "memory");
    __builtin_amdgcn_sched_barrier(0);
    __builtin_amdgcn_s_barrier();
    if (t + 2 < nt) stage((t + 2) * BK, b);
  }

  const int fq = lane >> 4;
#pragma unroll
  for (int n = 0; n < 4; ++n) {
    const long col = bcol + wc * 64 + n * 16 + fr;
    const float bv = bias[col];
#pragma unroll
    for (int m = 0; m < MF; ++m) {
#pragma unroll
      for (int rr = 0; rr < 4; ++rr) {
        const long row = brow + wr * (MF * 16) + m * 16 + fq * 4 + rr;
        float v = acc[m][n][rr] + bv;
        if (RELU) v = fmaxf(v, 0.0f);
        if (BF16_OUT)
          ((unsigned short*)Cout)[row * N + col] = f2bf(v);
        else
          ((float*)Cout)[row * N + col] = v;
      }
    }
  }
}

extern "C" void kernel_launch(void* const* d_in, const int* in_sizes, int n_in,
                              void* d_out, int out_size, void* d_ws, size_t ws_size,
                              hipStream_t stream) {
  const float* x  = (const float*)d_in[0];
  const float* w1 = (const float*)d_in[1];
  const float* b1 = (const float*)d_in[2];
  const float* w2 = (const float*)d_in[3];
  const float* b2 = (const float*)d_in[4];
  const int* bits = (const int*)d_in[5];

  const int M = 64 * 196;  // 12544 tokens
  const int D = 768, H = 3072;
  const int nx = M * D;
  const int nw1 = H * D;

  char* ws = (char*)d_ws;
  unsigned short* xb  = (unsigned short*)(ws + 256);
  unsigned short* w1q = (unsigned short*)(ws + 256 + (size_t)nx * 2);
  unsigned short* w2q = (unsigned short*)(ws + 256 + (size_t)nx * 2 + (size_t)nw1 * 2);
  unsigned short* hb  = (unsigned short*)(ws + 256 + (size_t)nx * 2 + (size_t)nw1 * 4);
  // pmax[2][512] aliased over hb's head: dead by the time GEMM1 writes hb
  // (prep -> quant2 -> GEMM1 are stream-serial; rewritten every call).
  unsigned int* pmax = (unsigned int*)hb;

  prep_kernel<<<dim3(512, 3), 256, 0, stream>>>(w1, w2, x, nw1 / 4, nx / 4, pmax, xb);
  quant2_kernel<<<dim3(512, 2), 256, 0, stream>>>(w1, w2, nw1 / 4, pmax, bits, w1q, w2q);

  // GEMM1: h = relu(x @ w1^T + b1), [12544,3072] bf16 ; 24x98 = 2352 blocks,
  // nt=24, 32KB LDS -> 3 blk/CU occupancy experiment
  gemm_bt32<true, true><<<(H / 128) * (M / 128), 256, 0, stream>>>(
      xb, w1q, b1, hb, M, H, D, H / 128);
  // GEMM2: out = h @ w2^T + b2, [12544,768] f32 ; 6x196 = 1176 blocks, nt=48,
  // 48KB LDS -> 3 blk/CU (round-11 frozen)
  gemm_bt<64, true, false, false><<<(D / 128) * (M / 64), 256, 0, stream>>>(
      hb, w2q, b2, d_out, M, D, H, D / 128);
}

// Round 13
// 183.935 us; speedup vs baseline: 1.2080x; 1.0026x over previous
//
#include <hip/hip_runtime.h>
#include <hip/hip_bf16.h>
#include <stdint.h>

typedef __attribute__((ext_vector_type(8))) short bf16x8;
typedef __attribute__((ext_vector_type(4))) float f32x4;

__device__ __forceinline__ unsigned short f2bf(float f) {
  __hip_bfloat16 h = __float2bfloat16(f);
  return *reinterpret_cast<unsigned short*>(&h);
}

// ---------------- prep: per-block absmax partials (y=0/1) + x->bf16 cast (y=2) ----------------
__global__ void prep_kernel(const float* __restrict__ w1, const float* __restrict__ w2,
                            const float* __restrict__ x, int n4w, int n4x,
                            unsigned int* __restrict__ pmax,
                            unsigned short* __restrict__ ox) {
  if (blockIdx.y == 2) {
    const float4* x4 = reinterpret_cast<const float4*>(x);
    ushort4* o4 = reinterpret_cast<ushort4*>(ox);
    for (int i = blockIdx.x * blockDim.x + threadIdx.x; i < n4x;
         i += gridDim.x * blockDim.x) {
      float4 v = x4[i];
      o4[i] = make_ushort4(f2bf(v.x), f2bf(v.y), f2bf(v.z), f2bf(v.w));
    }
    return;
  }
  const float* w = blockIdx.y ? w2 : w1;
  __shared__ unsigned int red[256];
  unsigned int m = 0u;
  const uint4* w4 = reinterpret_cast<const uint4*>(w);
  for (int i = blockIdx.x * blockDim.x + threadIdx.x; i < n4w;
       i += gridDim.x * blockDim.x) {
    uint4 v = w4[i];
    m = max(m, v.x & 0x7fffffffu);
    m = max(m, v.y & 0x7fffffffu);
    m = max(m, v.z & 0x7fffffffu);
    m = max(m, v.w & 0x7fffffffu);
  }
  red[threadIdx.x] = m;
  __syncthreads();
  for (int s = 128; s > 0; s >>= 1) {
    if ((int)threadIdx.x < s)
      red[threadIdx.x] = max(red[threadIdx.x], red[threadIdx.x + s]);
    __syncthreads();
  }
  if (threadIdx.x == 0) pmax[blockIdx.y * 512 + blockIdx.x] = red[0];
}

// ---------------- fake-quant w1/w2: reduce 512 partials, then quantize ----------------
__global__ void quant2_kernel(const float* __restrict__ w1, const float* __restrict__ w2,
                              int n4, const unsigned int* __restrict__ pmax,
                              const int* __restrict__ bits,
                              unsigned short* __restrict__ o1, unsigned short* __restrict__ o2) {
  __shared__ unsigned int red[256];
  const unsigned int* p = pmax + blockIdx.y * 512;
  red[threadIdx.x] = max(p[threadIdx.x], p[threadIdx.x + 256]);
  __syncthreads();
  for (int s = 128; s > 0; s >>= 1) {
    if ((int)threadIdx.x < s)
      red[threadIdx.x] = max(red[threadIdx.x], red[threadIdx.x + s]);
    __syncthreads();
  }
  const float qmax = (float)((1 << (*bits - 1)) - 1);
  const float scale = __uint_as_float(red[0]) / qmax;

  const float* w = blockIdx.y ? w2 : w1;
  unsigned short* o = blockIdx.y ? o2 : o1;
  const float4* w4 = reinterpret_cast<const float4*>(w);
  ushort4* o4 = reinterpret_cast<ushort4*>(o);
  for (int i = blockIdx.x * blockDim.x + threadIdx.x; i < n4;
       i += gridDim.x * blockDim.x) {
    float4 v = w4[i];
    float a = fminf(fmaxf(rintf(v.x / scale), -qmax), qmax) * scale;
    float b = fminf(fmaxf(rintf(v.y / scale), -qmax), qmax) * scale;
    float c = fminf(fmaxf(rintf(v.z / scale), -qmax), qmax) * scale;
    float d = fminf(fmaxf(rintf(v.w / scale), -qmax), qmax) * scale;
    o4[i] = make_ushort4(f2bf(a), f2bf(b), f2bf(c), f2bf(d));
  }
}

// ---------------- GEMM1: 128x128 tile, BK=32, dbuf + counted vmcnt(4), 4 blocks/CU ----------------
// Round-13 change: launch_bounds(256,3) -> (256,4). Round-12 measured
// VGPR 56 + 64 AGPR = 120 <= 128 cap at 16 waves/CU; LDS 4x32KB = 128KB <= 160.
// 4 independently-phased blocks/CU cover each other's vmcnt/barrier drains.
// Swizzle (rounds 5/6/12 verified, 0 conflicts): chunk = 16 rows x 32 elems;
// global source slot (lane&3)^((lane>>3)&3); ds_read slot fs^((row>>1)&3).
template<bool RELU, bool BF16_OUT>
__global__ __launch_bounds__(256, 4)
void gemm_bt32(const unsigned short* __restrict__ A,  // [M,K] bf16 bits
               const unsigned short* __restrict__ B,  // [N,K] bf16 bits
               const float* __restrict__ bias,        // [N]
               void* __restrict__ Cout,               // [M,N] bf16 or f32
               int M, int N, int K, int gx) {
  constexpr int BK = 32, MF = 4;
  __shared__ __attribute__((aligned(16))) unsigned short As[2][128 * BK];
  __shared__ __attribute__((aligned(16))) unsigned short Bs[2][128 * BK];

  // bijective XCD swizzle (T1/m204)
  const int nwg = gridDim.x;
  const int orig = blockIdx.x;
  const int q = nwg >> 3, r = nwg & 7;
  const int xcd = orig & 7, cidx = orig >> 3;
  const int wgid = (xcd < r ? xcd * (q + 1) : r * (q + 1) + (xcd - r) * q) + cidx;
  const int bx = wgid % gx;
  const int by = wgid / gx;

  const int tid = threadIdx.x;
  const int lane = tid & 63;
  const int wave = tid >> 6;
  const int wr = wave >> 1;
  const int wc = wave & 1;
  const long brow = (long)by * 128;
  const long bcol = (long)bx * 128;

  f32x4 acc[MF][4] = {};

  // staging: chunk = 16 rows x 32 elems (1KB)
  const int srow = lane >> 2;
  const int gslot = ((lane & 3) ^ ((lane >> 3) & 3)) * 8;
  const int fr = lane & 15;
  const int fs = lane >> 4;   // logical 16B k-slot (0..3)

  auto stage = [&](int k0, int b) {
#pragma unroll
    for (int it = 0; it < 2; ++it) {          // A: 8 chunks of 16 rows
      const int c = it * 4 + wave;
      const unsigned short* ga = A + (brow + c * 16 + srow) * (long)K + k0 + gslot;
      __builtin_amdgcn_global_load_lds(
          (const __attribute__((address_space(1))) void*)ga,
          (__attribute__((address_space(3))) void*)(&As[b][c * 512]), 16, 0, 0);
    }
#pragma unroll
    for (int it = 0; it < 2; ++it) {          // B: 8 chunks
      const int c = it * 4 + wave;
      const unsigned short* gb = B + (bcol + c * 16 + srow) * (long)K + k0 + gslot;
      __builtin_amdgcn_global_load_lds(
          (const __attribute__((address_space(1))) void*)gb,
          (__attribute__((address_space(3))) void*)(&Bs[b][c * 512]), 16, 0, 0);
    }
  };

  const int nt = K / BK;
  stage(0, 0);
  stage(BK, 1);

  for (int t = 0; t < nt; ++t) {
    const int b = t & 1;
    if (t < nt - 1) asm volatile("s_waitcnt vmcnt(4)" ::: "memory");
    else            asm volatile("s_waitcnt vmcnt(0)" ::: "memory");
    __builtin_amdgcn_s_barrier();

    const unsigned short* as = &As[b][0];
    const unsigned short* bs = &Bs[b][0];
    bf16x8 a[MF], bb[4];
#pragma unroll
    for (int m = 0; m < MF; ++m) {
      const int row = wr * 64 + m * 16 + fr;
      a[m] = *reinterpret_cast<const bf16x8*>(as + row * BK + ((fs ^ ((row >> 1) & 3)) * 8));
    }
#pragma unroll
    for (int n = 0; n < 4; ++n) {
      const int row = wc * 64 + n * 16 + fr;
      bb[n] = *reinterpret_cast<const bf16x8*>(bs + row * BK + ((fs ^ ((row >> 1) & 3)) * 8));
    }
#pragma unroll
    for (int m = 0; m < MF; ++m)
#pragma unroll
      for (int n = 0; n < 4; ++n)
        acc[m][n] = __builtin_amdgcn_mfma_f32_16x16x32_bf16(a[m], bb[n], acc[m][n], 0, 0, 0);

    asm volatile("s_waitcnt lgkmcnt(0)" ::: "memory");
    __builtin_amdgcn_sched_barrier(0);
    __builtin_amdgcn_s_barrier();
    if (t + 2 < nt) stage((t + 2) * BK, b);
  }

  // epilogue: C/D layout col=lane&15, row=(lane>>4)*4+rr  [m89/m91 verified]
  const int fq = lane >> 4;
#pragma unroll
  for (int n = 0; n < 4; ++n) {
    const long col = bcol + wc * 64 + n * 16 + fr;
    const float bv = bias[col];
#pragma unroll
    for (int m = 0; m < MF; ++m) {
#pragma unroll
      for (int rr = 0; rr < 4; ++rr) {
        const long row = brow + wr * 64 + m * 16 + fq * 4 + rr;
        float v = acc[m][n][rr] + bv;
        if (RELU) v = fmaxf(v, 0.0f);
        if (BF16_OUT)
          ((unsigned short*)Cout)[row * N + col] = f2bf(v);
        else
          ((float*)Cout)[row * N + col] = v;
      }
    }
  }
}

// ---------------- GEMM2: round-11 kernel frozen (BM=64, BK=64, 3 blk/CU, setprio) ----------------
template<int BM, bool PRIO, bool RELU, bool BF16_OUT>
__global__ __launch_bounds__(256)
void gemm_bt(const unsigned short* __restrict__ A, const unsigned short* __restrict__ B,
             const float* __restrict__ bias, void* __restrict__ Cout,
             int M, int N, int K, int gx) {
  constexpr int BK = 64;
  constexpr int MF = BM / 32;
  __shared__ __attribute__((aligned(16))) unsigned short As[2][BM * BK];
  __shared__ __attribute__((aligned(16))) unsigned short Bs[2][128 * BK];

  const int nwg = gridDim.x;
  const int orig = blockIdx.x;
  const int q = nwg >> 3, r = nwg & 7;
  const int xcd = orig & 7, cidx = orig >> 3;
  const int wgid = (xcd < r ? xcd * (q + 1) : r * (q + 1) + (xcd - r) * q) + cidx;
  const int bx = wgid % gx;
  const int by = wgid / gx;

  const int tid = threadIdx.x;
  const int lane = tid & 63;
  const int wave = tid >> 6;
  const int wr = wave >> 1;
  const int wc = wave & 1;
  const long brow = (long)by * BM;
  const long bcol = (long)bx * 128;

  f32x4 acc[MF][4] = {};

  const int srow = lane >> 3;
  const int gslot = ((lane & 7) ^ (lane >> 3)) * 8;
  const int fr = lane & 15;
  const int fs = lane >> 4;

  auto stage = [&](int k0, int b) {
#pragma unroll
    for (int it = 0; it < BM / 32; ++it) {
      const int c = it * 4 + wave;
      const unsigned short* ga = A + (brow + c * 8 + srow) * (long)K + k0 + gslot;
      __builtin_amdgcn_global_load_lds(
          (const __attribute__((address_space(1))) void*)ga,
          (__attribute__((address_space(3))) void*)(&As[b][c * 512]), 16, 0, 0);
    }
#pragma unroll
    for (int it = 0; it < 4; ++it) {
      const int c = it * 4 + wave;
      const unsigned short* gb = B + (bcol + c * 8 + srow) * (long)K + k0 + gslot;
      __builtin_amdgcn_global_load_lds(
          (const __attribute__((address_space(1))) void*)gb,
          (__attribute__((address_space(3))) void*)(&Bs[b][c * 512]), 16, 0, 0);
    }
  };

  const int nt = K / BK;
  stage(0, 0);
  stage(BK, 1);

  for (int t = 0; t < nt; ++t) {
    const int b = t & 1;
    if (t < nt - 1) {
      if constexpr (BM == 128) asm volatile("s_waitcnt vmcnt(8)" ::: "memory");
      else                     asm volatile("s_waitcnt vmcnt(6)" ::: "memory");
    } else {
      asm volatile("s_waitcnt vmcnt(0)" ::: "memory");
    }
    __builtin_amdgcn_s_barrier();

    const unsigned short* as = &As[b][0];
    const unsigned short* bs = &Bs[b][0];
#pragma unroll
    for (int kk = 0; kk < 2; ++kk) {
      const int s = kk * 4 + fs;
      bf16x8 a[MF], bb[4];
#pragma unroll
      for (int m = 0; m < MF; ++m) {
        const int row = wr * (MF * 16) + m * 16 + fr;
        a[m] = *reinterpret_cast<const bf16x8*>(as + row * BK + ((s ^ (row & 7)) * 8));
      }
#pragma unroll
      for (int n = 0; n < 4; ++n) {
        const int row = wc * 64 + n * 16 + fr;
        bb[n] = *reinterpret_cast<const bf16x8*>(bs + row * BK + ((s ^ (row & 7)) * 8));
      }
      if (PRIO) __builtin_amdgcn_s_setprio(1);
#pragma unroll
      for (int m = 0; m < MF; ++m)
#pragma unroll
        for (int n = 0; n < 4; ++n)
          acc[m][n] = __builtin_amdgcn_mfma_f32_16x16x32_bf16(a[m], bb[n], acc[m][n], 0, 0, 0);
      if (PRIO) __builtin_amdgcn_s_setprio(0);
    }

    asm volatile("s_waitcnt lgkmcnt(0)" ::: "memory");
    __builtin_amdgcn_sched_barrier(0);
    __builtin_amdgcn_s_barrier();
    if (t + 2 < nt) stage((t + 2) * BK, b);
  }

  const int fq = lane >> 4;
#pragma unroll
  for (int n = 0; n < 4; ++n) {
    const long col = bcol + wc * 64 + n * 16 + fr;
    const float bv = bias[col];
#pragma unroll
    for (int m = 0; m < MF; ++m) {
#pragma unroll
      for (int rr = 0; rr < 4; ++rr) {
        const long row = brow + wr * (MF * 16) + m * 16 + fq * 4 + rr;
        float v = acc[m][n][rr] + bv;
        if (RELU) v = fmaxf(v, 0.0f);
        if (BF16_OUT)
          ((unsigned short*)Cout)[row * N + col] = f2bf(v);
        else
          ((float*)Cout)[row * N + col] = v;
      }
    }
  }
}

extern "C" void kernel_launch(void* const* d_in, const int* in_sizes, int n_in,
                              void* d_out, int out_size, void* d_ws, size_t ws_size,
                              hipStream_t stream) {
  const float* x  = (const float*)d_in[0];
  const float* w1 = (const float*)d_in[1];
  const float* b1 = (const float*)d_in[2];
  const float* w2 = (const float*)d_in[3];
  const float* b2 = (const float*)d_in[4];
  const int* bits = (const int*)d_in[5];

  const int M = 64 * 196;  // 12544 tokens
  const int D = 768, H = 3072;
  const int nx = M * D;
  const int nw1 = H * D;

  char* ws = (char*)d_ws;
  unsigned short* xb  = (unsigned short*)(ws + 256);
  unsigned short* w1q = (unsigned short*)(ws + 256 + (size_t)nx * 2);
  unsigned short* w2q = (unsigned short*)(ws + 256 + (size_t)nx * 2 + (size_t)nw1 * 2);
  unsigned short* hb  = (unsigned short*)(ws + 256 + (size_t)nx * 2 + (size_t)nw1 * 4);
  // pmax[2][512] aliased over hb's head: dead by the time GEMM1 writes hb
  // (prep -> quant2 -> GEMM1 are stream-serial; rewritten every call).
  unsigned int* pmax = (unsigned int*)hb;

  prep_kernel<<<dim3(512, 3), 256, 0, stream>>>(w1, w2, x, nw1 / 4, nx / 4, pmax, xb);
  quant2_kernel<<<dim3(512, 2), 256, 0, stream>>>(w1, w2, nw1 / 4, pmax, bits, w1q, w2q);

  // GEMM1: h = relu(x @ w1^T + b1), [12544,3072] bf16 ; 24x98 = 2352 blocks,
  // nt=24, 32KB LDS, launch_bounds(256,4) -> 4 blk/CU occupancy push
  gemm_bt32<true, true><<<(H / 128) * (M / 128), 256, 0, stream>>>(
      xb, w1q, b1, hb, M, H, D, H / 128);
  // GEMM2: out = h @ w2^T + b2, [12544,768] f32 ; 6x196 = 1176 blocks, nt=48,
  // 48KB LDS -> 3 blk/CU (round-11 frozen)
  gemm_bt<64, true, false, false><<<(D / 128) * (M / 64), 256, 0, stream>>>(
      hb, w2q, b2, d_out, M, D, H, D / 128);
}